// Round 13
// baseline (1515.549 us; speedup 1.0000x reference)
//
#include <hip/hip_runtime.h>

// EQL forward, round 8 (resubmitted x5 — broker timeouts; kernel unmeasured).
// EXACT round-1 matmul structure (the only compile that never spilled:
// 136 VGPR, WRITE == output), with weights moved global -> LDS.
// Rounds 2-7 all spilled (256 VGPR, ~1.1GB scratch) and shared three deltas vs
// round 1: transposed [e][d] layout, float4-quad LDS reads, e-outer loop nest.
// This round keeps round 1's d-outer/e-inner SCALAR reads and untransposed
// layout; the single variable vs round 1 is weight residence (LDS vs global).
//   kernel 1 (mask):  constw[s,o,j] = constw_base[o,j]*((hard-soft)+soft) -> d_ws
//   kernel 2 (main):  one block per (s,o,chunk); weights+bias staged to LDS,
//                     broadcast scalar ds_reads; hidden[94] in VGPRs.
//   kernel 3 (fin):   out[983040] = regu_sum / (S*B*O)

#define S_NUM 16
#define O_NUM 15
#define B_NUM 4096
#define NET_IN 64
#define WSHAPE 3120
#define BSHAPE 41
#define TEMP_F 0.03f
#define EPS_F 1e-20f
#define OUT_ELEMS (S_NUM * B_NUM * O_NUM)   // 983040
#define BIAS_OFF WSHAPE                     // bias offset inside LDS

// ---------------------------------------------------------------- mask kernel
__global__ __launch_bounds__(256) void eql_mask_kernel(
    const float* __restrict__ scores, const float* __restrict__ constw_base,
    const float* __restrict__ u0, const float* __restrict__ u1,
    float* __restrict__ wsw)
{
  int idx = blockIdx.x * 256 + threadIdx.x;
  if (idx >= S_NUM * O_NUM * WSHAPE) return;
  int oj = idx % (O_NUM * WSHAPE);

  float a0 = u0[idx], a1 = u1[idx];
  float noise = -logf(logf(a0 + EPS_F) / logf(a1 + EPS_F) + EPS_F);
  float sc = scores[oj];
  float cs = 1.0f / (1.0f + expf(-sc));
  float arg = (logf(cs + EPS_F) - logf(1.0f - cs + EPS_F) + noise) * TEMP_F;
  float soft = 1.0f / (1.0f + expf(-arg));
  float hard = (soft > 0.5f) ? 1.0f : 0.0f;
  // forward value of hard - stop_gradient(soft) + soft, replicated exactly
  wsw[idx] = constw_base[oj] * ((hard - soft) + soft);
}

// ---------------------------------------------------------------- ops
__device__ __forceinline__ float clip100(float x) {
  return fminf(fmaxf(x, -100.f), 100.f);
}
__device__ __forceinline__ float op_mul(float a, float b, float& r) {
  r += fmaxf(-100.f - a, 0.f) + fmaxf(a - 100.f, 0.f)
     + fmaxf(-100.f - b, 0.f) + fmaxf(b - 100.f, 0.f);
  return clip100(a) * clip100(b);
}
__device__ __forceinline__ float op_div(float a, float b, float& r) {
  r += fmaxf(0.01f - b, 0.f);
  return (b < 0.01f) ? 0.f : a / b;
}
__device__ __forceinline__ float op_log(float a, float& r) {
  r += fmaxf(0.001f - a, 0.f);
  return logf(fmaxf(a, 0.001f));
}
__device__ __forceinline__ float op_exp(float a, float& r) {
  r += fmaxf(-10.f - a, 0.f) + fmaxf(a - 4.f, 0.f);
  return expf(fminf(fmaxf(a, -10.f), 4.f));
}

// ROUND-1 matmul macro, verbatim structure (d-outer, e-inner, scalar reads);
// only the base array changed from global `w` to LDS `wl`.
// pre[e] = wl[BIAS_OFF+BLO+e] + sum_d h[d] * wl[WLO + d*INALL + e]
#define DO_MM(INS, INALL, WLO, BLO, P)                                   \
  float P[INALL];                                                        \
  _Pragma("unroll") for (int e = 0; e < (INALL); e++)                    \
      P[e] = wl[BIAS_OFF + (BLO) + e];                                   \
  _Pragma("unroll") for (int d = 0; d < (INS); d++) {                    \
    float hd = h[d];                                                     \
    _Pragma("unroll") for (int e = 0; e < (INALL); e++)                  \
      P[e] = fmaf(wl[(WLO) + d * (INALL) + e], hd, P[e]);                \
  }

// ---------------------------------------------------------------- main kernel
__global__ __launch_bounds__(256) void eql_main_kernel(
    const float* __restrict__ obs, const float* __restrict__ constb,
    const float* __restrict__ wsw, float* __restrict__ out,
    double* __restrict__ regu_acc)
{
  __shared__ __align__(16) float wl[WSHAPE + BSHAPE + 3];  // 12.6 KB

  int blk = blockIdx.x;
  int chunk = blk & 15;          // 16 chunks of 256 batch rows
  int so = blk >> 4;             // 0..239
  int o = so % O_NUM;
  int s = so / O_NUM;

  // stage weights (3120 floats = 780 float4) + biases into LDS
  {
    const float4* src = reinterpret_cast<const float4*>(wsw + (size_t)so * WSHAPE);
    float4* dst = reinterpret_cast<float4*>(wl);
    for (int i = threadIdx.x; i < WSHAPE / 4; i += 256) dst[i] = src[i];
    if (threadIdx.x < BSHAPE) wl[BIAS_OFF + threadIdx.x] = constb[o * BSHAPE + threadIdx.x];
  }
  __syncthreads();

  int b = chunk * 256 + threadIdx.x;

  float h[94];
  const float4* o4 = reinterpret_cast<const float4*>(obs + (size_t)b * NET_IN);
#pragma unroll
  for (int i = 0; i < 16; i++) {
    float4 v = o4[i];
    h[4 * i] = v.x; h[4 * i + 1] = v.y; h[4 * i + 2] = v.z; h[4 * i + 3] = v.w;
  }

  float regu = 0.f;

  { // layer 0: mul,mul,mul          ins=64 inall=6 wlo=0    blo=0
    DO_MM(64, 6, 0, 0, p)
    h[64] = op_mul(p[0], p[1], regu);
    h[65] = op_mul(p[2], p[3], regu);
    h[66] = op_mul(p[4], p[5], regu);
  }
  { // layer 1: div,div,div          ins=67 inall=6 wlo=384  blo=6
    DO_MM(67, 6, 384, 6, p)
    h[67] = op_div(p[0], p[1], regu);
    h[68] = op_div(p[2], p[3], regu);
    h[69] = op_div(p[4], p[5], regu);
  }
  { // layer 2: log,log,exp,exp,sin,sin,cos,cos  ins=70 inall=8 wlo=786 blo=12
    DO_MM(70, 8, 786, 12, p)
    h[70] = op_log(p[0], regu);
    h[71] = op_log(p[1], regu);
    h[72] = op_exp(p[2], regu);
    h[73] = op_exp(p[3], regu);
    h[74] = sinf(p[4]);
    h[75] = sinf(p[5]);
    h[76] = cosf(p[6]);
    h[77] = cosf(p[7]);
  }
  { // layer 3: same                 ins=78 inall=8 wlo=1346 blo=20
    DO_MM(78, 8, 1346, 20, p)
    h[78] = op_log(p[0], regu);
    h[79] = op_log(p[1], regu);
    h[80] = op_exp(p[2], regu);
    h[81] = op_exp(p[3], regu);
    h[82] = sinf(p[4]);
    h[83] = sinf(p[5]);
    h[84] = cosf(p[6]);
    h[85] = cosf(p[7]);
  }
  { // layer 4: mul,div,log,exp      ins=86 inall=6 wlo=1970 blo=28
    DO_MM(86, 6, 1970, 28, p)
    h[86] = op_mul(p[0], p[1], regu);
    h[87] = op_div(p[2], p[3], regu);
    h[88] = op_log(p[4], regu);
    h[89] = op_exp(p[5], regu);
  }
  { // layer 5: mul,div,log,exp      ins=90 inall=6 wlo=2486 blo=34
    DO_MM(90, 6, 2486, 34, p)
    h[90] = op_mul(p[0], p[1], regu);
    h[91] = op_div(p[2], p[3], regu);
    h[92] = op_log(p[4], regu);
    h[93] = op_exp(p[5], regu);
  }

  // final: ins=94, 1 output, wlo=3026, blo=40
  float res = wl[BIAS_OFF + 40];
#pragma unroll
  for (int d = 0; d < 94; d++) res = fmaf(wl[3026 + d], h[d], res);

  out[((size_t)s * B_NUM + b) * O_NUM + o] = res;

  // ---- regu block reduction -> one f64 atomic per block
#pragma unroll
  for (int off = 32; off > 0; off >>= 1) regu += __shfl_down(regu, off);
  __shared__ float wsum[4];
  if ((threadIdx.x & 63) == 0) wsum[threadIdx.x >> 6] = regu;
  __syncthreads();
  if (threadIdx.x == 0) {
    float t = wsum[0] + wsum[1] + wsum[2] + wsum[3];
    atomicAdd(regu_acc, (double)t);
  }
}

// ---------------------------------------------------------------- finalize
__global__ void eql_finalize_kernel(const double* __restrict__ regu_acc,
                                    float* __restrict__ out)
{
  out[OUT_ELEMS] = (float)(*regu_acc / (double)OUT_ELEMS);
}

// ---------------------------------------------------------------- launch
extern "C" void kernel_launch(void* const* d_in, const int* in_sizes, int n_in,
                              void* d_out, int out_size, void* d_ws, size_t ws_size,
                              hipStream_t stream) {
  const float* obs    = (const float*)d_in[0];
  const float* scores = (const float*)d_in[1];
  const float* cwb    = (const float*)d_in[2];
  const float* constb = (const float*)d_in[3];
  const float* u0     = (const float*)d_in[4];
  const float* u1     = (const float*)d_in[5];
  float* out = (float*)d_out;

  double* regu = (double*)d_ws;                       // 8 B accumulator
  float*  wsw  = (float*)((char*)d_ws + 256);         // 16*15*3120 floats ~ 3 MB

  hipMemsetAsync(regu, 0, sizeof(double), stream);

  int n_mask = S_NUM * O_NUM * WSHAPE;                // 748800
  eql_mask_kernel<<<(n_mask + 255) / 256, 256, 0, stream>>>(scores, cwb, u0, u1, wsw);

  eql_main_kernel<<<S_NUM * O_NUM * (B_NUM / 256), 256, 0, stream>>>(
      obs, constb, wsw, out, regu);

  eql_finalize_kernel<<<1, 1, 0, stream>>>(regu, out);
}

// Round 15
// 750.875 us; speedup vs baseline: 2.0184x; 2.0184x over previous
//
#include <hip/hip_runtime.h>

// EQL forward, round 14 (resubmitted — broker timeout; R=2 unmeasured).
// Round-1 compile shape (global scalarized weight reads, d-outer/e-inner
// macro — the ONLY no-spill form; 136 VGPR, SGPR 112) + R=2 batch rows/thread.
// Round-13 verdict: LDS weight residence spills in EVERY variant tried
// (5 structures, all 256 VGPR + >1GB scratch) -> LDS abandoned.
// Round-1 bottleneck was the serialized s_load weight chain (~390 packets
// x ~200cyc, ~1 block/CU). R=2 halves waves (each weight load feeds 2 rows)
// and doubles independent FMA streams behind the chain.
//   kernel 1 (mask): constw[s,o,j] = constw_base[o,j]*((hard-soft)+soft) -> d_ws
//   kernel 2 (main): one block per (s,o,chunk); 256 threads x 2 rows = 512 rows.
//   kernel 3 (fin):  out[983040] = regu_sum / (S*B*O)

#define S_NUM 16
#define O_NUM 15
#define B_NUM 4096
#define NET_IN 64
#define WSHAPE 3120
#define BSHAPE 41
#define TEMP_F 0.03f
#define EPS_F 1e-20f
#define OUT_ELEMS (S_NUM * B_NUM * O_NUM)   // 983040

// ---------------------------------------------------------------- mask kernel
__global__ __launch_bounds__(256) void eql_mask_kernel(
    const float* __restrict__ scores, const float* __restrict__ constw_base,
    const float* __restrict__ u0, const float* __restrict__ u1,
    float* __restrict__ wsw)
{
  int idx = blockIdx.x * 256 + threadIdx.x;
  if (idx >= S_NUM * O_NUM * WSHAPE) return;
  int oj = idx % (O_NUM * WSHAPE);

  float a0 = u0[idx], a1 = u1[idx];
  float noise = -logf(logf(a0 + EPS_F) / logf(a1 + EPS_F) + EPS_F);
  float sc = scores[oj];
  float cs = 1.0f / (1.0f + expf(-sc));
  float arg = (logf(cs + EPS_F) - logf(1.0f - cs + EPS_F) + noise) * TEMP_F;
  float soft = 1.0f / (1.0f + expf(-arg));
  float hard = (soft > 0.5f) ? 1.0f : 0.0f;
  // forward value of hard - stop_gradient(soft) + soft, replicated exactly
  wsw[idx] = constw_base[oj] * ((hard - soft) + soft);
}

// ---------------------------------------------------------------- ops
__device__ __forceinline__ float clip100(float x) {
  return fminf(fmaxf(x, -100.f), 100.f);
}
__device__ __forceinline__ float op_mul(float a, float b, float& r) {
  r += fmaxf(-100.f - a, 0.f) + fmaxf(a - 100.f, 0.f)
     + fmaxf(-100.f - b, 0.f) + fmaxf(b - 100.f, 0.f);
  return clip100(a) * clip100(b);
}
__device__ __forceinline__ float op_div(float a, float b, float& r) {
  r += fmaxf(0.01f - b, 0.f);
  return (b < 0.01f) ? 0.f : a / b;
}
__device__ __forceinline__ float op_log(float a, float& r) {
  r += fmaxf(0.001f - a, 0.f);
  return logf(fmaxf(a, 0.001f));
}
__device__ __forceinline__ float op_exp(float a, float& r) {
  r += fmaxf(-10.f - a, 0.f) + fmaxf(a - 4.f, 0.f);
  return expf(fminf(fmaxf(a, -10.f), 4.f));
}

// ROUND-1 matmul macro, d-outer / e-inner, scalar global reads (compiler
// scalarizes the wave-uniform w[] access to s_load -> SGPRs, no VGPR blowup).
// R=2: one weight value feeds both rows' fmacs.
#define DO_MM2(INS, INALL, WLO, BLO)                                     \
  float pA[INALL], pB[INALL];                                            \
  _Pragma("unroll") for (int e = 0; e < (INALL); e++) {                  \
    float bv = bb[(BLO) + e];                                            \
    pA[e] = bv; pB[e] = bv;                                              \
  }                                                                      \
  _Pragma("unroll") for (int d = 0; d < (INS); d++) {                    \
    float hdA = hA[d], hdB = hB[d];                                      \
    _Pragma("unroll") for (int e = 0; e < (INALL); e++) {                \
      float wv = w[(WLO) + d * (INALL) + e];                             \
      pA[e] = fmaf(wv, hdA, pA[e]);                                      \
      pB[e] = fmaf(wv, hdB, pB[e]);                                      \
    }                                                                    \
  }

// ---------------------------------------------------------------- main kernel
__global__ __launch_bounds__(256) void eql_main_kernel(
    const float* __restrict__ obs, const float* __restrict__ constb,
    const float* __restrict__ wsw, float* __restrict__ out,
    double* __restrict__ regu_acc)
{
  int blk = blockIdx.x;
  int chunk = blk & 7;           // 8 chunks of 512 batch rows
  int so = blk >> 3;             // 0..239
  int o = so % O_NUM;
  int s = so / O_NUM;

  const float* __restrict__ w  = wsw + (size_t)so * WSHAPE;  // wave-uniform
  const float* __restrict__ bb = constb + o * BSHAPE;        // wave-uniform

  int bA = chunk * 512 + threadIdx.x;        // row A
  int bB = bA + 256;                         // row B

  float hA[94], hB[94];
  {
    const float4* oA = reinterpret_cast<const float4*>(obs + (size_t)bA * NET_IN);
    const float4* oB = reinterpret_cast<const float4*>(obs + (size_t)bB * NET_IN);
#pragma unroll
    for (int i = 0; i < 16; i++) {
      float4 va = oA[i];
      hA[4 * i] = va.x; hA[4 * i + 1] = va.y; hA[4 * i + 2] = va.z; hA[4 * i + 3] = va.w;
      float4 vb = oB[i];
      hB[4 * i] = vb.x; hB[4 * i + 1] = vb.y; hB[4 * i + 2] = vb.z; hB[4 * i + 3] = vb.w;
    }
  }

  float regu = 0.f;

  { // layer 0: mul,mul,mul          ins=64 inall=6 wlo=0    blo=0
    DO_MM2(64, 6, 0, 0)
    hA[64] = op_mul(pA[0], pA[1], regu);
    hA[65] = op_mul(pA[2], pA[3], regu);
    hA[66] = op_mul(pA[4], pA[5], regu);
    hB[64] = op_mul(pB[0], pB[1], regu);
    hB[65] = op_mul(pB[2], pB[3], regu);
    hB[66] = op_mul(pB[4], pB[5], regu);
  }
  { // layer 1: div,div,div          ins=67 inall=6 wlo=384  blo=6
    DO_MM2(67, 6, 384, 6)
    hA[67] = op_div(pA[0], pA[1], regu);
    hA[68] = op_div(pA[2], pA[3], regu);
    hA[69] = op_div(pA[4], pA[5], regu);
    hB[67] = op_div(pB[0], pB[1], regu);
    hB[68] = op_div(pB[2], pB[3], regu);
    hB[69] = op_div(pB[4], pB[5], regu);
  }
  { // layer 2: log,log,exp,exp,sin,sin,cos,cos  ins=70 inall=8 wlo=786 blo=12
    DO_MM2(70, 8, 786, 12)
    hA[70] = op_log(pA[0], regu);
    hA[71] = op_log(pA[1], regu);
    hA[72] = op_exp(pA[2], regu);
    hA[73] = op_exp(pA[3], regu);
    hA[74] = sinf(pA[4]);
    hA[75] = sinf(pA[5]);
    hA[76] = cosf(pA[6]);
    hA[77] = cosf(pA[7]);
    hB[70] = op_log(pB[0], regu);
    hB[71] = op_log(pB[1], regu);
    hB[72] = op_exp(pB[2], regu);
    hB[73] = op_exp(pB[3], regu);
    hB[74] = sinf(pB[4]);
    hB[75] = sinf(pB[5]);
    hB[76] = cosf(pB[6]);
    hB[77] = cosf(pB[7]);
  }
  { // layer 3: same                 ins=78 inall=8 wlo=1346 blo=20
    DO_MM2(78, 8, 1346, 20)
    hA[78] = op_log(pA[0], regu);
    hA[79] = op_log(pA[1], regu);
    hA[80] = op_exp(pA[2], regu);
    hA[81] = op_exp(pA[3], regu);
    hA[82] = sinf(pA[4]);
    hA[83] = sinf(pA[5]);
    hA[84] = cosf(pA[6]);
    hA[85] = cosf(pA[7]);
    hB[78] = op_log(pB[0], regu);
    hB[79] = op_log(pB[1], regu);
    hB[80] = op_exp(pB[2], regu);
    hB[81] = op_exp(pB[3], regu);
    hB[82] = sinf(pB[4]);
    hB[83] = sinf(pB[5]);
    hB[84] = cosf(pB[6]);
    hB[85] = cosf(pB[7]);
  }
  { // layer 4: mul,div,log,exp      ins=86 inall=6 wlo=1970 blo=28
    DO_MM2(86, 6, 1970, 28)
    hA[86] = op_mul(pA[0], pA[1], regu);
    hA[87] = op_div(pA[2], pA[3], regu);
    hA[88] = op_log(pA[4], regu);
    hA[89] = op_exp(pA[5], regu);
    hB[86] = op_mul(pB[0], pB[1], regu);
    hB[87] = op_div(pB[2], pB[3], regu);
    hB[88] = op_log(pB[4], regu);
    hB[89] = op_exp(pB[5], regu);
  }
  { // layer 5: mul,div,log,exp      ins=90 inall=6 wlo=2486 blo=34
    DO_MM2(90, 6, 2486, 34)
    hA[90] = op_mul(pA[0], pA[1], regu);
    hA[91] = op_div(pA[2], pA[3], regu);
    hA[92] = op_log(pA[4], regu);
    hA[93] = op_exp(pA[5], regu);
    hB[90] = op_mul(pB[0], pB[1], regu);
    hB[91] = op_div(pB[2], pB[3], regu);
    hB[92] = op_log(pB[4], regu);
    hB[93] = op_exp(pB[5], regu);
  }

  // final: ins=94, 1 output, wlo=3026, blo=40
  float resA = bb[40];
  float resB = bb[40];
#pragma unroll
  for (int d = 0; d < 94; d++) {
    float wv = w[3026 + d];
    resA = fmaf(wv, hA[d], resA);
    resB = fmaf(wv, hB[d], resB);
  }

  out[((size_t)s * B_NUM + bA) * O_NUM + o] = resA;
  out[((size_t)s * B_NUM + bB) * O_NUM + o] = resB;

  // ---- regu block reduction -> one f64 atomic per block
#pragma unroll
  for (int off = 32; off > 0; off >>= 1) regu += __shfl_down(regu, off);
  __shared__ float wsum[4];
  if ((threadIdx.x & 63) == 0) wsum[threadIdx.x >> 6] = regu;
  __syncthreads();
  if (threadIdx.x == 0) {
    float t = wsum[0] + wsum[1] + wsum[2] + wsum[3];
    atomicAdd(regu_acc, (double)t);
  }
}

// ---------------------------------------------------------------- finalize
__global__ void eql_finalize_kernel(const double* __restrict__ regu_acc,
                                    float* __restrict__ out)
{
  out[OUT_ELEMS] = (float)(*regu_acc / (double)OUT_ELEMS);
}

// ---------------------------------------------------------------- launch
extern "C" void kernel_launch(void* const* d_in, const int* in_sizes, int n_in,
                              void* d_out, int out_size, void* d_ws, size_t ws_size,
                              hipStream_t stream) {
  const float* obs    = (const float*)d_in[0];
  const float* scores = (const float*)d_in[1];
  const float* cwb    = (const float*)d_in[2];
  const float* constb = (const float*)d_in[3];
  const float* u0     = (const float*)d_in[4];
  const float* u1     = (const float*)d_in[5];
  float* out = (float*)d_out;

  double* regu = (double*)d_ws;                       // 8 B accumulator
  float*  wsw  = (float*)((char*)d_ws + 256);         // 16*15*3120 floats ~ 3 MB

  hipMemsetAsync(regu, 0, sizeof(double), stream);

  int n_mask = S_NUM * O_NUM * WSHAPE;                // 748800
  eql_mask_kernel<<<(n_mask + 255) / 256, 256, 0, stream>>>(scores, cwb, u0, u1, wsw);

  // 240 (s,o) x 8 chunks of 512 rows (256 threads x 2 rows each)
  eql_main_kernel<<<S_NUM * O_NUM * (B_NUM / 512), 256, 0, stream>>>(
      obs, constb, wsw, out, regu);

  eql_finalize_kernel<<<1, 1, 0, stream>>>(regu, out);
}

// Round 16
// 588.809 us; speedup vs baseline: 2.5739x; 1.2752x over previous
//
#include <hip/hip_runtime.h>

// EQL forward, round 16: round-15 kernel + XCD-aware block mapping.
// Round-15 counters: FETCH 25.5MB = 1920 blocks x 12.5KB weights -> EVERY
// block's weight chain missed to HBM (~900cyc/packet), because blk=so*8+chunk
// put chunk in the low bits: the 8 chunks sharing one (s,o)'s weights were
// round-robined onto 8 DIFFERENT XCDs (non-coherent L2s). Fix: decode
// so = blk % 240, chunk = blk / 240. 240 % 8 == 0 -> all chunks of one so land
// on XCD so%8; each XCD L2 holds its 30 weight sets (375KB) + the shared
// 128KB obs chunk -> weight reads become L2 hits after the first round.
//   kernel 1 (mask): constw[s,o,j] = constw_base[o,j]*((hard-soft)+soft) -> d_ws
//   kernel 2 (main): one block per (s,o,chunk); 256 threads x 2 rows = 512 rows.
//   kernel 3 (fin):  out[983040] = regu_sum / (S*B*O)

#define S_NUM 16
#define O_NUM 15
#define B_NUM 4096
#define NET_IN 64
#define WSHAPE 3120
#define BSHAPE 41
#define TEMP_F 0.03f
#define EPS_F 1e-20f
#define OUT_ELEMS (S_NUM * B_NUM * O_NUM)   // 983040

// ---------------------------------------------------------------- mask kernel
__global__ __launch_bounds__(256) void eql_mask_kernel(
    const float* __restrict__ scores, const float* __restrict__ constw_base,
    const float* __restrict__ u0, const float* __restrict__ u1,
    float* __restrict__ wsw)
{
  int idx = blockIdx.x * 256 + threadIdx.x;
  if (idx >= S_NUM * O_NUM * WSHAPE) return;
  int oj = idx % (O_NUM * WSHAPE);

  float a0 = u0[idx], a1 = u1[idx];
  float noise = -logf(logf(a0 + EPS_F) / logf(a1 + EPS_F) + EPS_F);
  float sc = scores[oj];
  float cs = 1.0f / (1.0f + expf(-sc));
  float arg = (logf(cs + EPS_F) - logf(1.0f - cs + EPS_F) + noise) * TEMP_F;
  float soft = 1.0f / (1.0f + expf(-arg));
  float hard = (soft > 0.5f) ? 1.0f : 0.0f;
  // forward value of hard - stop_gradient(soft) + soft, replicated exactly
  wsw[idx] = constw_base[oj] * ((hard - soft) + soft);
}

// ---------------------------------------------------------------- ops
__device__ __forceinline__ float clip100(float x) {
  return fminf(fmaxf(x, -100.f), 100.f);
}
__device__ __forceinline__ float op_mul(float a, float b, float& r) {
  r += fmaxf(-100.f - a, 0.f) + fmaxf(a - 100.f, 0.f)
     + fmaxf(-100.f - b, 0.f) + fmaxf(b - 100.f, 0.f);
  return clip100(a) * clip100(b);
}
__device__ __forceinline__ float op_div(float a, float b, float& r) {
  r += fmaxf(0.01f - b, 0.f);
  return (b < 0.01f) ? 0.f : a / b;
}
__device__ __forceinline__ float op_log(float a, float& r) {
  r += fmaxf(0.001f - a, 0.f);
  return logf(fmaxf(a, 0.001f));
}
__device__ __forceinline__ float op_exp(float a, float& r) {
  r += fmaxf(-10.f - a, 0.f) + fmaxf(a - 4.f, 0.f);
  return expf(fminf(fmaxf(a, -10.f), 4.f));
}

// ROUND-1 matmul macro, d-outer / e-inner, scalar global reads (compiler
// scalarizes the wave-uniform w[] access to s_load -> SGPRs, no VGPR blowup).
// R=2: one weight value feeds both rows' fmacs.
#define DO_MM2(INS, INALL, WLO, BLO)                                     \
  float pA[INALL], pB[INALL];                                            \
  _Pragma("unroll") for (int e = 0; e < (INALL); e++) {                  \
    float bv = bb[(BLO) + e];                                            \
    pA[e] = bv; pB[e] = bv;                                              \
  }                                                                      \
  _Pragma("unroll") for (int d = 0; d < (INS); d++) {                    \
    float hdA = hA[d], hdB = hB[d];                                      \
    _Pragma("unroll") for (int e = 0; e < (INALL); e++) {                \
      float wv = w[(WLO) + d * (INALL) + e];                             \
      pA[e] = fmaf(wv, hdA, pA[e]);                                      \
      pB[e] = fmaf(wv, hdB, pB[e]);                                      \
    }                                                                    \
  }

// ---------------------------------------------------------------- main kernel
__global__ __launch_bounds__(256) void eql_main_kernel(
    const float* __restrict__ obs, const float* __restrict__ constb,
    const float* __restrict__ wsw, float* __restrict__ out,
    double* __restrict__ regu_acc)
{
  int blk = blockIdx.x;
  // XCD-aware decode: all 8 chunks of one so share XCD so%8 (240 % 8 == 0).
  int so    = blk % (S_NUM * O_NUM);   // 0..239
  int chunk = blk / (S_NUM * O_NUM);   // 0..7
  int o = so % O_NUM;
  int s = so / O_NUM;

  const float* __restrict__ w  = wsw + (size_t)so * WSHAPE;  // wave-uniform
  const float* __restrict__ bb = constb + o * BSHAPE;        // wave-uniform

  int bA = chunk * 512 + threadIdx.x;        // row A
  int bB = bA + 256;                         // row B

  float hA[94], hB[94];
  {
    const float4* oA = reinterpret_cast<const float4*>(obs + (size_t)bA * NET_IN);
    const float4* oB = reinterpret_cast<const float4*>(obs + (size_t)bB * NET_IN);
#pragma unroll
    for (int i = 0; i < 16; i++) {
      float4 va = oA[i];
      hA[4 * i] = va.x; hA[4 * i + 1] = va.y; hA[4 * i + 2] = va.z; hA[4 * i + 3] = va.w;
      float4 vb = oB[i];
      hB[4 * i] = vb.x; hB[4 * i + 1] = vb.y; hB[4 * i + 2] = vb.z; hB[4 * i + 3] = vb.w;
    }
  }

  float regu = 0.f;

  { // layer 0: mul,mul,mul          ins=64 inall=6 wlo=0    blo=0
    DO_MM2(64, 6, 0, 0)
    hA[64] = op_mul(pA[0], pA[1], regu);
    hA[65] = op_mul(pA[2], pA[3], regu);
    hA[66] = op_mul(pA[4], pA[5], regu);
    hB[64] = op_mul(pB[0], pB[1], regu);
    hB[65] = op_mul(pB[2], pB[3], regu);
    hB[66] = op_mul(pB[4], pB[5], regu);
  }
  { // layer 1: div,div,div          ins=67 inall=6 wlo=384  blo=6
    DO_MM2(67, 6, 384, 6)
    hA[67] = op_div(pA[0], pA[1], regu);
    hA[68] = op_div(pA[2], pA[3], regu);
    hA[69] = op_div(pA[4], pA[5], regu);
    hB[67] = op_div(pB[0], pB[1], regu);
    hB[68] = op_div(pB[2], pB[3], regu);
    hB[69] = op_div(pB[4], pB[5], regu);
  }
  { // layer 2: log,log,exp,exp,sin,sin,cos,cos  ins=70 inall=8 wlo=786 blo=12
    DO_MM2(70, 8, 786, 12)
    hA[70] = op_log(pA[0], regu);
    hA[71] = op_log(pA[1], regu);
    hA[72] = op_exp(pA[2], regu);
    hA[73] = op_exp(pA[3], regu);
    hA[74] = sinf(pA[4]);
    hA[75] = sinf(pA[5]);
    hA[76] = cosf(pA[6]);
    hA[77] = cosf(pA[7]);
    hB[70] = op_log(pB[0], regu);
    hB[71] = op_log(pB[1], regu);
    hB[72] = op_exp(pB[2], regu);
    hB[73] = op_exp(pB[3], regu);
    hB[74] = sinf(pB[4]);
    hB[75] = sinf(pB[5]);
    hB[76] = cosf(pB[6]);
    hB[77] = cosf(pB[7]);
  }
  { // layer 3: same                 ins=78 inall=8 wlo=1346 blo=20
    DO_MM2(78, 8, 1346, 20)
    hA[78] = op_log(pA[0], regu);
    hA[79] = op_log(pA[1], regu);
    hA[80] = op_exp(pA[2], regu);
    hA[81] = op_exp(pA[3], regu);
    hA[82] = sinf(pA[4]);
    hA[83] = sinf(pA[5]);
    hA[84] = cosf(pA[6]);
    hA[85] = cosf(pA[7]);
    hB[78] = op_log(pB[0], regu);
    hB[79] = op_log(pB[1], regu);
    hB[80] = op_exp(pB[2], regu);
    hB[81] = op_exp(pB[3], regu);
    hB[82] = sinf(pB[4]);
    hB[83] = sinf(pB[5]);
    hB[84] = cosf(pB[6]);
    hB[85] = cosf(pB[7]);
  }
  { // layer 4: mul,div,log,exp      ins=86 inall=6 wlo=1970 blo=28
    DO_MM2(86, 6, 1970, 28)
    hA[86] = op_mul(pA[0], pA[1], regu);
    hA[87] = op_div(pA[2], pA[3], regu);
    hA[88] = op_log(pA[4], regu);
    hA[89] = op_exp(pA[5], regu);
    hB[86] = op_mul(pB[0], pB[1], regu);
    hB[87] = op_div(pB[2], pB[3], regu);
    hB[88] = op_log(pB[4], regu);
    hB[89] = op_exp(pB[5], regu);
  }
  { // layer 5: mul,div,log,exp      ins=90 inall=6 wlo=2486 blo=34
    DO_MM2(90, 6, 2486, 34)
    hA[90] = op_mul(pA[0], pA[1], regu);
    hA[91] = op_div(pA[2], pA[3], regu);
    hA[92] = op_log(pA[4], regu);
    hA[93] = op_exp(pA[5], regu);
    hB[90] = op_mul(pB[0], pB[1], regu);
    hB[91] = op_div(pB[2], pB[3], regu);
    hB[92] = op_log(pB[4], regu);
    hB[93] = op_exp(pB[5], regu);
  }

  // final: ins=94, 1 output, wlo=3026, blo=40
  float resA = bb[40];
  float resB = bb[40];
#pragma unroll
  for (int d = 0; d < 94; d++) {
    float wv = w[3026 + d];
    resA = fmaf(wv, hA[d], resA);
    resB = fmaf(wv, hB[d], resB);
  }

  out[((size_t)s * B_NUM + bA) * O_NUM + o] = resA;
  out[((size_t)s * B_NUM + bB) * O_NUM + o] = resB;

  // ---- regu block reduction -> one f64 atomic per block
#pragma unroll
  for (int off = 32; off > 0; off >>= 1) regu += __shfl_down(regu, off);
  __shared__ float wsum[4];
  if ((threadIdx.x & 63) == 0) wsum[threadIdx.x >> 6] = regu;
  __syncthreads();
  if (threadIdx.x == 0) {
    float t = wsum[0] + wsum[1] + wsum[2] + wsum[3];
    atomicAdd(regu_acc, (double)t);
  }
}

// ---------------------------------------------------------------- finalize
__global__ void eql_finalize_kernel(const double* __restrict__ regu_acc,
                                    float* __restrict__ out)
{
  out[OUT_ELEMS] = (float)(*regu_acc / (double)OUT_ELEMS);
}

// ---------------------------------------------------------------- launch
extern "C" void kernel_launch(void* const* d_in, const int* in_sizes, int n_in,
                              void* d_out, int out_size, void* d_ws, size_t ws_size,
                              hipStream_t stream) {
  const float* obs    = (const float*)d_in[0];
  const float* scores = (const float*)d_in[1];
  const float* cwb    = (const float*)d_in[2];
  const float* constb = (const float*)d_in[3];
  const float* u0     = (const float*)d_in[4];
  const float* u1     = (const float*)d_in[5];
  float* out = (float*)d_out;

  double* regu = (double*)d_ws;                       // 8 B accumulator
  float*  wsw  = (float*)((char*)d_ws + 256);         // 16*15*3120 floats ~ 3 MB

  hipMemsetAsync(regu, 0, sizeof(double), stream);

  int n_mask = S_NUM * O_NUM * WSHAPE;                // 748800
  eql_mask_kernel<<<(n_mask + 255) / 256, 256, 0, stream>>>(scores, cwb, u0, u1, wsw);

  // 240 (s,o) x 8 chunks of 512 rows; so = blk % 240 keeps all chunks of one
  // so on a single XCD (blockIdx round-robins XCDs, 240 % 8 == 0).
  eql_main_kernel<<<S_NUM * O_NUM * (B_NUM / 512), 256, 0, stream>>>(
      obs, constb, wsw, out, regu);

  eql_finalize_kernel<<<1, 1, 0, stream>>>(regu, out);
}

// Round 17
// 584.859 us; speedup vs baseline: 2.5913x; 1.0068x over previous
//
#include <hip/hip_runtime.h>

// EQL forward, round 17: persistent per-(s,o) blocks for weight-stream reuse.
// Round-16 confirmed the weight path is the lever (FETCH 25.5->8.35MB, 687->528us
// via XCD swizzle). Remaining stall: every one of 1920 blocks re-streamed its
// 12.5KB weight set L2-cold (~780 scalarized s_load packets x ~200cyc, ~1 wave/
// SIMD of hiding -> VALUBusy 51%). This round: grid = 240 blocks (one per (s,o),
// <= 256 CUs so one block per CU, no cache competition), looping chunk=0..7
// internally (R=2, 512 rows/pass). Pass 1 warms K$/L2; passes 2-8 re-stream warm.
//   kernel 1 (mask): constw[s,o,j] = constw_base[o,j]*((hard-soft)+soft) -> d_ws
//   kernel 2 (main): 240 blocks x 256 threads; 8 passes x 2 rows per thread.
//   kernel 3 (fin):  out[983040] = regu_sum / (S*B*O)

#define S_NUM 16
#define O_NUM 15
#define B_NUM 4096
#define NET_IN 64
#define WSHAPE 3120
#define BSHAPE 41
#define TEMP_F 0.03f
#define EPS_F 1e-20f
#define OUT_ELEMS (S_NUM * B_NUM * O_NUM)   // 983040

// ---------------------------------------------------------------- mask kernel
__global__ __launch_bounds__(256) void eql_mask_kernel(
    const float* __restrict__ scores, const float* __restrict__ constw_base,
    const float* __restrict__ u0, const float* __restrict__ u1,
    float* __restrict__ wsw)
{
  int idx = blockIdx.x * 256 + threadIdx.x;
  if (idx >= S_NUM * O_NUM * WSHAPE) return;
  int oj = idx % (O_NUM * WSHAPE);

  float a0 = u0[idx], a1 = u1[idx];
  float noise = -logf(logf(a0 + EPS_F) / logf(a1 + EPS_F) + EPS_F);
  float sc = scores[oj];
  float cs = 1.0f / (1.0f + expf(-sc));
  float arg = (logf(cs + EPS_F) - logf(1.0f - cs + EPS_F) + noise) * TEMP_F;
  float soft = 1.0f / (1.0f + expf(-arg));
  float hard = (soft > 0.5f) ? 1.0f : 0.0f;
  // forward value of hard - stop_gradient(soft) + soft, replicated exactly
  wsw[idx] = constw_base[oj] * ((hard - soft) + soft);
}

// ---------------------------------------------------------------- ops
__device__ __forceinline__ float clip100(float x) {
  return fminf(fmaxf(x, -100.f), 100.f);
}
__device__ __forceinline__ float op_mul(float a, float b, float& r) {
  r += fmaxf(-100.f - a, 0.f) + fmaxf(a - 100.f, 0.f)
     + fmaxf(-100.f - b, 0.f) + fmaxf(b - 100.f, 0.f);
  return clip100(a) * clip100(b);
}
__device__ __forceinline__ float op_div(float a, float b, float& r) {
  r += fmaxf(0.01f - b, 0.f);
  return (b < 0.01f) ? 0.f : a / b;
}
__device__ __forceinline__ float op_log(float a, float& r) {
  r += fmaxf(0.001f - a, 0.f);
  return logf(fmaxf(a, 0.001f));
}
__device__ __forceinline__ float op_exp(float a, float& r) {
  r += fmaxf(-10.f - a, 0.f) + fmaxf(a - 4.f, 0.f);
  return expf(fminf(fmaxf(a, -10.f), 4.f));
}

// ROUND-1 matmul macro, d-outer / e-inner, scalar global reads (compiler
// scalarizes the wave-uniform w[] access to s_load -> SGPRs, no VGPR blowup).
// R=2: one weight value feeds both rows' fmacs.
#define DO_MM2(INS, INALL, WLO, BLO)                                     \
  float pA[INALL], pB[INALL];                                            \
  _Pragma("unroll") for (int e = 0; e < (INALL); e++) {                  \
    float bv = bb[(BLO) + e];                                            \
    pA[e] = bv; pB[e] = bv;                                              \
  }                                                                      \
  _Pragma("unroll") for (int d = 0; d < (INS); d++) {                    \
    float hdA = hA[d], hdB = hB[d];                                      \
    _Pragma("unroll") for (int e = 0; e < (INALL); e++) {                \
      float wv = w[(WLO) + d * (INALL) + e];                             \
      pA[e] = fmaf(wv, hdA, pA[e]);                                      \
      pB[e] = fmaf(wv, hdB, pB[e]);                                      \
    }                                                                    \
  }

// ---------------------------------------------------------------- main kernel
__global__ __launch_bounds__(256) void eql_main_kernel(
    const float* __restrict__ obs, const float* __restrict__ constb,
    const float* __restrict__ wsw, float* __restrict__ out,
    double* __restrict__ regu_acc)
{
  int so = blockIdx.x;           // 0..239, one (s,o) per block == per CU
  int o = so % O_NUM;
  int s = so / O_NUM;

  const float* __restrict__ w  = wsw + (size_t)so * WSHAPE;  // wave-uniform
  const float* __restrict__ bb = constb + o * BSHAPE;        // wave-uniform

  float regu = 0.f;

#pragma unroll 1
  for (int chunk = 0; chunk < B_NUM / 512; ++chunk) {
    int bA = chunk * 512 + threadIdx.x;      // row A
    int bB = bA + 256;                       // row B

    float hA[94], hB[94];
    {
      const float4* oA = reinterpret_cast<const float4*>(obs + (size_t)bA * NET_IN);
      const float4* oB = reinterpret_cast<const float4*>(obs + (size_t)bB * NET_IN);
#pragma unroll
      for (int i = 0; i < 16; i++) {
        float4 va = oA[i];
        hA[4 * i] = va.x; hA[4 * i + 1] = va.y; hA[4 * i + 2] = va.z; hA[4 * i + 3] = va.w;
        float4 vb = oB[i];
        hB[4 * i] = vb.x; hB[4 * i + 1] = vb.y; hB[4 * i + 2] = vb.z; hB[4 * i + 3] = vb.w;
      }
    }

    { // layer 0: mul,mul,mul          ins=64 inall=6 wlo=0    blo=0
      DO_MM2(64, 6, 0, 0)
      hA[64] = op_mul(pA[0], pA[1], regu);
      hA[65] = op_mul(pA[2], pA[3], regu);
      hA[66] = op_mul(pA[4], pA[5], regu);
      hB[64] = op_mul(pB[0], pB[1], regu);
      hB[65] = op_mul(pB[2], pB[3], regu);
      hB[66] = op_mul(pB[4], pB[5], regu);
    }
    { // layer 1: div,div,div          ins=67 inall=6 wlo=384  blo=6
      DO_MM2(67, 6, 384, 6)
      hA[67] = op_div(pA[0], pA[1], regu);
      hA[68] = op_div(pA[2], pA[3], regu);
      hA[69] = op_div(pA[4], pA[5], regu);
      hB[67] = op_div(pB[0], pB[1], regu);
      hB[68] = op_div(pB[2], pB[3], regu);
      hB[69] = op_div(pB[4], pB[5], regu);
    }
    { // layer 2: log,log,exp,exp,sin,sin,cos,cos  ins=70 inall=8 wlo=786 blo=12
      DO_MM2(70, 8, 786, 12)
      hA[70] = op_log(pA[0], regu);
      hA[71] = op_log(pA[1], regu);
      hA[72] = op_exp(pA[2], regu);
      hA[73] = op_exp(pA[3], regu);
      hA[74] = sinf(pA[4]);
      hA[75] = sinf(pA[5]);
      hA[76] = cosf(pA[6]);
      hA[77] = cosf(pA[7]);
      hB[70] = op_log(pB[0], regu);
      hB[71] = op_log(pB[1], regu);
      hB[72] = op_exp(pB[2], regu);
      hB[73] = op_exp(pB[3], regu);
      hB[74] = sinf(pB[4]);
      hB[75] = sinf(pB[5]);
      hB[76] = cosf(pB[6]);
      hB[77] = cosf(pB[7]);
    }
    { // layer 3: same                 ins=78 inall=8 wlo=1346 blo=20
      DO_MM2(78, 8, 1346, 20)
      hA[78] = op_log(pA[0], regu);
      hA[79] = op_log(pA[1], regu);
      hA[80] = op_exp(pA[2], regu);
      hA[81] = op_exp(pA[3], regu);
      hA[82] = sinf(pA[4]);
      hA[83] = sinf(pA[5]);
      hA[84] = cosf(pA[6]);
      hA[85] = cosf(pA[7]);
      hB[78] = op_log(pB[0], regu);
      hB[79] = op_log(pB[1], regu);
      hB[80] = op_exp(pB[2], regu);
      hB[81] = op_exp(pB[3], regu);
      hB[82] = sinf(pB[4]);
      hB[83] = sinf(pB[5]);
      hB[84] = cosf(pB[6]);
      hB[85] = cosf(pB[7]);
    }
    { // layer 4: mul,div,log,exp      ins=86 inall=6 wlo=1970 blo=28
      DO_MM2(86, 6, 1970, 28)
      hA[86] = op_mul(pA[0], pA[1], regu);
      hA[87] = op_div(pA[2], pA[3], regu);
      hA[88] = op_log(pA[4], regu);
      hA[89] = op_exp(pA[5], regu);
      hB[86] = op_mul(pB[0], pB[1], regu);
      hB[87] = op_div(pB[2], pB[3], regu);
      hB[88] = op_log(pB[4], regu);
      hB[89] = op_exp(pB[5], regu);
    }
    { // layer 5: mul,div,log,exp      ins=90 inall=6 wlo=2486 blo=34
      DO_MM2(90, 6, 2486, 34)
      hA[90] = op_mul(pA[0], pA[1], regu);
      hA[91] = op_div(pA[2], pA[3], regu);
      hA[92] = op_log(pA[4], regu);
      hA[93] = op_exp(pA[5], regu);
      hB[90] = op_mul(pB[0], pB[1], regu);
      hB[91] = op_div(pB[2], pB[3], regu);
      hB[92] = op_log(pB[4], regu);
      hB[93] = op_exp(pB[5], regu);
    }

    // final: ins=94, 1 output, wlo=3026, blo=40
    float resA = bb[40];
    float resB = bb[40];
#pragma unroll
    for (int d = 0; d < 94; d++) {
      float wv = w[3026 + d];
      resA = fmaf(wv, hA[d], resA);
      resB = fmaf(wv, hB[d], resB);
    }

    out[((size_t)s * B_NUM + bA) * O_NUM + o] = resA;
    out[((size_t)s * B_NUM + bB) * O_NUM + o] = resB;
  }

  // ---- regu block reduction -> one f64 atomic per block
#pragma unroll
  for (int off = 32; off > 0; off >>= 1) regu += __shfl_down(regu, off);
  __shared__ float wsum[4];
  if ((threadIdx.x & 63) == 0) wsum[threadIdx.x >> 6] = regu;
  __syncthreads();
  if (threadIdx.x == 0) {
    float t = wsum[0] + wsum[1] + wsum[2] + wsum[3];
    atomicAdd(regu_acc, (double)t);
  }
}

// ---------------------------------------------------------------- finalize
__global__ void eql_finalize_kernel(const double* __restrict__ regu_acc,
                                    float* __restrict__ out)
{
  out[OUT_ELEMS] = (float)(*regu_acc / (double)OUT_ELEMS);
}

// ---------------------------------------------------------------- launch
extern "C" void kernel_launch(void* const* d_in, const int* in_sizes, int n_in,
                              void* d_out, int out_size, void* d_ws, size_t ws_size,
                              hipStream_t stream) {
  const float* obs    = (const float*)d_in[0];
  const float* scores = (const float*)d_in[1];
  const float* cwb    = (const float*)d_in[2];
  const float* constb = (const float*)d_in[3];
  const float* u0     = (const float*)d_in[4];
  const float* u1     = (const float*)d_in[5];
  float* out = (float*)d_out;

  double* regu = (double*)d_ws;                       // 8 B accumulator
  float*  wsw  = (float*)((char*)d_ws + 256);         // 16*15*3120 floats ~ 3 MB

  hipMemsetAsync(regu, 0, sizeof(double), stream);

  int n_mask = S_NUM * O_NUM * WSHAPE;                // 748800
  eql_mask_kernel<<<(n_mask + 255) / 256, 256, 0, stream>>>(scores, cwb, u0, u1, wsw);

  // one block per (s,o): each CU owns one 12.5KB weight set for the whole
  // kernel; 8 internal chunk passes re-stream it cache-warm.
  eql_main_kernel<<<S_NUM * O_NUM, 256, 0, stream>>>(
      obs, constb, wsw, out, regu);

  eql_finalize_kernel<<<1, 1, 0, stream>>>(regu, out);
}